// Round 5
// baseline (105.463 us; speedup 1.0000x reference)
//
#include <hip/hip_runtime.h>

// Chamfer loss, N=4, P1=P2=8192, D=3, K=1.
// prep: points -> float4(-2x,-2y,-2z,|p|^2), padded targets w=1e30 (no masking later).
// main: block=(dir,b,256-row group,1024-col segment); rows from coalesced dwordx4;
//       col tiles async-staged via global_load_lds into double-buffered LDS,
//       prefetch issued before compute, one barrier/tile. 3 fma + min3 per 2 pairs.
// reduce: min over segments, clamp, scale, block-sum, atomicAdd.
constexpr int N = 4;
constexpr int P = 8192;
constexpr int NSEG = 8;
constexpr int SEGC = P / NSEG;      // 1024 cols per segment
constexpr int TILE = 256;
constexpr int MI = 8;               // rows per thread
constexpr int ROWS = 256;           // rows per block
constexpr int RG = P / ROWS;        // 32
constexpr size_t TRANS_F = (size_t)2 * N * P * 4;   // floats used by trans arrays

__global__ __launch_bounds__(256) void chamfer_prep_kernel(
    const float* __restrict__ pred, const float* __restrict__ targ,
    const int* __restrict__ lens, float4* __restrict__ trans)
{
    const int i = blockIdx.x * 256 + threadIdx.x;    // 0 .. 2*N*P-1
    const int side = i >> 15;                        // 0: pred, 1: targ
    const int b    = (i >> 13) & (N - 1);
    const int j    = i & (P - 1);
    const float* s = (side ? targ : pred) + ((size_t)b * P + j) * 3;
    const float x = s[0], y = s[1], z = s[2];
    float w = fmaf(x, x, fmaf(y, y, z * z));
    if (side == 1 && j >= lens[b]) w = 1e30f;        // padded target: never wins min
    trans[i] = make_float4(-2.f * x, -2.f * y, -2.f * z, w);
}

__global__ __launch_bounds__(256) void chamfer_min_kernel(
    const int* __restrict__ lens, const float4* __restrict__ trans,
    float* __restrict__ partial)
{
    const int seg = blockIdx.y;
    int id = blockIdx.x;                   // 2*N*RG = 256
    const int rg  = id & (RG - 1); id >>= 5;
    const int b   = id & (N - 1);  id >>= 2;
    const int dir = id;                    // 0: pred rows / targ cols
    const int row0 = rg * ROWS;
    const int c0   = seg * SEGC;
    const int L    = lens[b];
    const int tid  = threadIdx.x;
    const int chunk   = tid >> 5;          // 0..7: 32-col slice of tile
    const int rowtile = tid & 31;
    const int wave = tid >> 6, lane = tid & 63;

    float* slot = partial + (((size_t)dir * N + b) * NSEG + seg) * P + row0;
    if (dir == 1 && row0 >= L) return;               // rows never read
    if (dir == 0 && c0 >= L) { slot[tid] = 1e30f; return; }

    const float4* rsrc = trans + ((size_t)(dir == 0 ? 0 : 1) * N + b) * P;
    const float4* csrc = trans + ((size_t)(dir == 0 ? 1 : 0) * N + b) * P;

    float rx[MI], ry[MI], rz[MI], rw[MI], best[MI];
    #pragma unroll
    for (int k = 0; k < MI; ++k) {
        const float4 t = rsrc[row0 + rowtile + 32 * k];   // one dwordx4, coalesced
        rx[k] = -0.5f * t.x; ry[k] = -0.5f * t.y; rz[k] = -0.5f * t.z;
        rw[k] = t.w;                                      // |row|^2 (or 1e30 pad, masked later)
        best[k] = 1e30f;
    }

    __shared__ float4 buf[2][TILE];        // double-buffered column tiles
    __shared__ float  red[ROWS * 9];       // 8 chunk-mins + |row|^2, stride 9

    int vc = SEGC;
    if (dir == 0 && L - c0 < SEGC) vc = L - c0;
    const int nt = (vc + TILE - 1) / TILE; // padded cols inside a tile are w=1e30: no mask

    // async-stage tile 0
    __builtin_amdgcn_global_load_lds(
        (const __attribute__((address_space(1))) void*)(csrc + c0 + wave * 64 + lane),
        (__attribute__((address_space(3))) void*)&buf[0][wave * 64], 16, 0, 0);
    __syncthreads();                       // drain: tile 0 resident

    for (int t = 0; t < nt; ++t) {
        const int cur = t & 1;
        if (t + 1 < nt)                    // prefetch BEFORE compute: latency hides under it
            __builtin_amdgcn_global_load_lds(
                (const __attribute__((address_space(1))) void*)(csrc + c0 + (t + 1) * TILE + wave * 64 + lane),
                (__attribute__((address_space(3))) void*)&buf[cur ^ 1][wave * 64], 16, 0, 0);

        const float4* sp = &buf[cur][chunk * 32];
        #pragma unroll 4
        for (int jj = 0; jj < 32; jj += 2) {
            const float4 q0 = sp[jj];
            const float4 q1 = sp[jj + 1];
            #pragma unroll
            for (int k = 0; k < MI; ++k) {
                float d0 = fmaf(rx[k], q0.x, fmaf(ry[k], q0.y, fmaf(rz[k], q0.z, q0.w)));
                float d1 = fmaf(rx[k], q1.x, fmaf(ry[k], q1.y, fmaf(rz[k], q1.z, q1.w)));
                best[k] = fminf(best[k], fminf(d0, d1));   // -> v_min3_f32
            }
        }
        __syncthreads();                   // readers done with buf[cur]; prefetch drained
    }

    #pragma unroll
    for (int k = 0; k < MI; ++k)
        red[(rowtile + 32 * k) * 9 + chunk] = best[k];
    if (chunk == 0) {
        #pragma unroll
        for (int k = 0; k < MI; ++k)
            red[(rowtile + 32 * k) * 9 + 8] = rw[k];
    }
    __syncthreads();

    {   // one row per thread: 8-way min + |row|^2 -> partial
        const float* r = &red[tid * 9];
        float v = fminf(fminf(fminf(r[0], r[1]), fminf(r[2], r[3])),
                        fminf(fminf(r[4], r[5]), fminf(r[6], r[7])));
        slot[tid] = v + r[8];
    }
}

__global__ __launch_bounds__(256) void chamfer_reduce_kernel(
    const float* __restrict__ partial, const int* __restrict__ lens,
    float* __restrict__ out)
{
    const int item = blockIdx.x * 256 + threadIdx.x;     // 2*N*P = 65536
    const int dir = item >> 15;
    const int b   = (item >> 13) & (N - 1);
    const int p   = item & (P - 1);
    const int L   = lens[b];

    float c = 0.f;
    if (dir == 0 || p < L) {
        const float* base = partial + (((size_t)dir * N + b) * NSEG) * P + p;
        float v = base[0];
        #pragma unroll
        for (int s = 1; s < NSEG; ++s) v = fminf(v, base[(size_t)s * P]);
        v = fmaxf(v, 0.f);
        c = dir ? v / ((float)L * (float)N) : v * (1.0f / ((float)P * (float)N));
    }
    #pragma unroll
    for (int off = 32; off; off >>= 1) c += __shfl_down(c, off, 64);
    __shared__ float acc[4];
    if ((threadIdx.x & 63) == 0) acc[threadIdx.x >> 6] = c;
    __syncthreads();
    if (threadIdx.x == 0) atomicAdd(out, acc[0] + acc[1] + acc[2] + acc[3]);
}

extern "C" void kernel_launch(void* const* d_in, const int* in_sizes, int n_in,
                              void* d_out, int out_size, void* d_ws, size_t ws_size,
                              hipStream_t stream)
{
    const float* pred = (const float*)d_in[0];
    const float* targ = (const float*)d_in[1];
    const int*   lens = (const int*)d_in[2];
    float* out = (float*)d_out;
    float4* trans   = (float4*)d_ws;                 // 1 MB
    float*  partial = (float*)d_ws + TRANS_F;        // 2 MB

    hipMemsetAsync(out, 0, out_size * sizeof(float), stream);
    chamfer_prep_kernel<<<(2 * N * P) / 256, 256, 0, stream>>>(pred, targ, lens, trans);
    dim3 grid(2 * N * RG, NSEG);                     // 2048 blocks
    chamfer_min_kernel<<<grid, 256, 0, stream>>>(lens, trans, partial);
    chamfer_reduce_kernel<<<(2 * N * P) / 256, 256, 0, stream>>>(partial, lens, out);
}